// Round 10
// baseline (234.498 us; speedup 1.0000x reference)
//
#include <hip/hip_runtime.h>
#include <math.h>

#define HEADS 4
#define CH 64
#define HID 256
#define IN_DIM 768
#define NEG_SLOPE 0.2f

typedef _Float16 f16x8 __attribute__((ext_vector_type(8)));
typedef _Float16 f16x4 __attribute__((ext_vector_type(4)));
typedef float f32x4 __attribute__((ext_vector_type(4)));

__device__ __forceinline__ void async16(void* lds, const void* g) {
  __builtin_amdgcn_global_load_lds(
      (const __attribute__((address_space(1))) unsigned int*)g,
      (__attribute__((address_space(3))) unsigned int*)lds, 16, 0, 0);
}

// ---------------------------------------------------------------------------
// prep: wconv W1 + wconv W2 + degree histogram, fused (block-range split)
// ---------------------------------------------------------------------------
#define G1 768   /* IN_DIM*HID/256 */
#define G2 256   /* HID*HID/256 */
__global__ void prep_kernel(const float* __restrict__ W1, _Float16* __restrict__ W1t,
                            const float* __restrict__ W2, _Float16* __restrict__ W2t,
                            const int* __restrict__ edge_dst, int* __restrict__ deg,
                            int E, int ET) {
  const int b = blockIdx.x;
  if (b < G1) {
    const int idx = b * 256 + threadIdx.x;
    const int k = idx >> 8, n = idx & 255;
    W1t[(size_t)n * IN_DIM + k] = (_Float16)W1[idx];
  } else if (b < G1 + G2) {
    const int idx = (b - G1) * 256 + threadIdx.x;
    const int k = idx >> 8, n = idx & 255;
    W2t[(size_t)n * HID + k] = (_Float16)W2[idx];
  } else {
    const int e = (b - G1 - G2) * 256 + threadIdx.x;
    if (e < ET) {
      const int d = (e < E) ? edge_dst[e] : (e - E);
      atomicAdd(&deg[d], 1);
    }
  }
}

// ---------------------------------------------------------------------------
// Barrier-free streaming GEMM. Tile 16 rows x 256 cols, 256 thr = 4 waves
// (wave = head). The block's ENTIRE A panel (16 rows x K, contiguous 48KB
// fp32 / 8KB fp16) is staged in ONE global_load_lds burst -> ONE barrier ->
// 24 uninterrupted K-steps (A from LDS w/ inline cvt, B fragments direct
// from global; Bt is per-XCD-L2 resident). No per-K-tile barrier = no
// vmcnt(0) drain stall; 3 blocks/CU (48KB LDS) give cross-block overlap.
// A fetch is perfectly sequential (block k reads bytes [k*48KB,(k+1)*48KB)).
// XOR-swizzle via pre-swizzled source (rule 21): LDS slot (row,c) holds
// global chunk with low4 of c XOR'd by row -> conflict-free-enough (2-way).
// Fused per-wave alpha epilogue (wave owns one head).
// ---------------------------------------------------------------------------
template <bool AF16, int K>
__global__ __launch_bounds__(256, 3) void gemm_stream(
    const void* __restrict__ Av, const _Float16* __restrict__ Bt,
    _Float16* __restrict__ C, const float* __restrict__ a_src,
    const float* __restrict__ a_dst, float* __restrict__ al_s4,
    float* __restrict__ al_d4, int M) {
  constexpr int ROWS = 16;
  constexpr int EB = AF16 ? 2 : 4;   // element bytes
  constexpr int RB = K * EB;         // bytes per row
  constexpr int CHUNKS = RB / 16;    // 16B chunks per row
  constexpr int PER_T = (ROWS * CHUNKS) / 256;
  __shared__ char Ab[ROWS * RB];

  const int t = threadIdx.x;
  const int lane = t & 63;
  const int hd = t >> 6;             // wave = head
  const int row0 = blockIdx.x * ROWS;
  const int rl = lane & 15;
  const int qk = lane >> 4;

  // ---- stage whole A panel in one burst (pre-swizzled source chunks)
#pragma unroll
  for (int j = 0; j < PER_T; ++j) {
    const int s = j * 256 + t;
    const int row = s / CHUNKS;
    const int c = s - row * CHUNKS;
    const int cp = (c & ~15) | ((c ^ row) & 15);
    const int rg = min(row0 + row, M - 1);
    async16(Ab + s * 16, (const char*)Av + (size_t)rg * RB + cp * 16);
  }

  const _Float16* pb[4];
#pragma unroll
  for (int n = 0; n < 4; ++n)
    pb[n] = Bt + (size_t)(hd * 64 + n * 16 + rl) * K + qk * 8;

  __syncthreads();                   // the ONLY barrier: DMA drained

  f32x4 acc[4] = {};
#pragma unroll
  for (int ks = 0; ks < K / 32; ++ks) {
    f16x8 af;
    if (AF16) {
      const int c = ks * 4 + qk;
      const int cp = (c & ~15) | ((c ^ rl) & 15);
      af = *reinterpret_cast<const f16x8*>(Ab + rl * RB + cp * 16);
    } else {
      const int c0 = ks * 8 + qk * 2;
      const int cp0 = (c0 & ~15) | ((c0 ^ rl) & 15);
      const int cp1 = ((c0 + 1) & ~15) | (((c0 + 1) ^ rl) & 15);
      const f32x4 lo = *reinterpret_cast<const f32x4*>(Ab + rl * RB + cp0 * 16);
      const f32x4 hi = *reinterpret_cast<const f32x4*>(Ab + rl * RB + cp1 * 16);
      af = (f16x8){(_Float16)lo[0], (_Float16)lo[1], (_Float16)lo[2],
                   (_Float16)lo[3], (_Float16)hi[0], (_Float16)hi[1],
                   (_Float16)hi[2], (_Float16)hi[3]};
    }
    f16x8 bf[4];
#pragma unroll
    for (int n = 0; n < 4; ++n)
      bf[n] = *reinterpret_cast<const f16x8*>(pb[n] + ks * 32);
#pragma unroll
    for (int n = 0; n < 4; ++n)
      acc[n] = __builtin_amdgcn_mfma_f32_16x16x32_f16(af, bf[n], acc[n], 0, 0, 0);
  }

  // ---- C store (frag: row=(lane>>4)*4+r, col=lane&15)
#pragma unroll
  for (int n = 0; n < 4; ++n)
#pragma unroll
    for (int r = 0; r < 4; ++r) {
      const int gr = row0 + qk * 4 + r;
      if (gr < M)
        C[(size_t)gr * HID + hd * CH + n * 16 + rl] = (_Float16)acc[n][r];
    }

  // ---- fused alpha (wave owns head hd for its 16 rows; no LDS/atomics)
  const float as0 = a_src[hd * CH + rl];
  const float as1 = a_src[hd * CH + 16 + rl];
  const float as2 = a_src[hd * CH + 32 + rl];
  const float as3 = a_src[hd * CH + 48 + rl];
  const float ad0 = a_dst[hd * CH + rl];
  const float ad1 = a_dst[hd * CH + 16 + rl];
  const float ad2 = a_dst[hd * CH + 32 + rl];
  const float ad3 = a_dst[hd * CH + 48 + rl];
#pragma unroll
  for (int r = 0; r < 4; ++r) {
    float vs = acc[0][r] * as0 + acc[1][r] * as1 +
               acc[2][r] * as2 + acc[3][r] * as3;
    float vd = acc[0][r] * ad0 + acc[1][r] * ad1 +
               acc[2][r] * ad2 + acc[3][r] * ad3;
    vs += __shfl_xor(vs, 1); vs += __shfl_xor(vs, 2);
    vs += __shfl_xor(vs, 4); vs += __shfl_xor(vs, 8);
    vd += __shfl_xor(vd, 1); vd += __shfl_xor(vd, 2);
    vd += __shfl_xor(vd, 4); vd += __shfl_xor(vd, 8);
    const int gr = row0 + qk * 4 + r;
    if (rl == 0 && gr < M) {
      al_s4[gr * HEADS + hd] = vs;
      al_d4[gr * HEADS + hd] = vd;
    }
  }
}

// ---------------------------------------------------------------------------
// x4-vectorized single-block scan
// ---------------------------------------------------------------------------
__global__ __launch_bounds__(1024) void scan_kernel(const int* __restrict__ deg,
                                                    int* __restrict__ row_ptr, int n) {
  __shared__ int wsum[16];
  __shared__ int carry_s;
  const int t = threadIdx.x, lane = t & 63, w = t >> 6;
  if (t == 0) {
    carry_s = 0;
    row_ptr[0] = 0;
  }
  __syncthreads();
  for (int base = 0; base < n; base += 4096) {
    const int i0 = base + t * 4;
    int4 v = make_int4(0, 0, 0, 0);
    if (i0 < n) v = *reinterpret_cast<const int4*>(&deg[i0]);
    const int s0 = v.x, s1 = s0 + v.y, s2 = s1 + v.z, s3 = s2 + v.w;
    int x = s3;
#pragma unroll
    for (int off = 1; off < 64; off <<= 1) {
      int y = __shfl_up(x, off);
      if (lane >= off) x += y;
    }
    if (lane == 63) wsum[w] = x;
    __syncthreads();
    if (w == 0) {
      int s = (lane < 16) ? wsum[lane] : 0;
#pragma unroll
      for (int off = 1; off < 16; off <<= 1) {
        int y = __shfl_up(s, off);
        if (lane >= off) s += y;
      }
      if (lane < 16) wsum[lane] = s;
    }
    __syncthreads();
    const int woff = (w > 0) ? wsum[w - 1] : 0;
    const int pre = carry_s + woff + x - s3;
    if (i0 < n) {
      row_ptr[i0 + 1] = pre + s0;
      row_ptr[i0 + 2] = pre + s1;
      row_ptr[i0 + 3] = pre + s2;
      row_ptr[i0 + 4] = pre + s3;
    }
    __syncthreads();
    if (t == 1023) carry_s = pre + s3;
    __syncthreads();
  }
}

// ---------------------------------------------------------------------------
// scatter + layer-1 logits fused (after GEMM1)
// ---------------------------------------------------------------------------
__global__ void scatter_kernel(const int* __restrict__ edge_src,
                               const int* __restrict__ edge_dst,
                               const int* __restrict__ row_ptr,
                               int* __restrict__ cursor,
                               int* __restrict__ ssrc, int* __restrict__ sdst,
                               const float* __restrict__ al_s4,
                               const float* __restrict__ al_d4,
                               float4* __restrict__ e4, int E, int ET) {
  const int e = blockIdx.x * blockDim.x + threadIdx.x;
  if (e < ET) {
    int d, s;
    if (e < E) {
      d = edge_dst[e];
      s = edge_src[e];
    } else {
      d = s = e - E;
    }
    const int pos = row_ptr[d] + atomicAdd(&cursor[d], 1);
    ssrc[pos] = s;
    sdst[pos] = d;
    const float4 as = *reinterpret_cast<const float4*>(&al_s4[s * 4]);
    const float4 ad = *reinterpret_cast<const float4*>(&al_d4[d * 4]);
    float4 ev;
    ev.x = as.x + ad.x; ev.x = (ev.x > 0.f) ? ev.x : NEG_SLOPE * ev.x;
    ev.y = as.y + ad.y; ev.y = (ev.y > 0.f) ? ev.y : NEG_SLOPE * ev.y;
    ev.z = as.z + ad.z; ev.z = (ev.z > 0.f) ? ev.z : NEG_SLOPE * ev.z;
    ev.w = as.w + ad.w; ev.w = (ev.w > 0.f) ? ev.w : NEG_SLOPE * ev.w;
    e4[pos] = ev;
  }
}

// layer-2 logits (CSR order already built)
__global__ __launch_bounds__(256) void logits_kernel(
    const float* __restrict__ al_s4, const float* __restrict__ al_d4,
    const int* __restrict__ ssrc, const int* __restrict__ sdst,
    float4* __restrict__ e4, int ET) {
  const int i = blockIdx.x * blockDim.x + threadIdx.x;
  if (i >= ET) return;
  const int s = ssrc[i];
  const int d = sdst[i];
  const float4 as = *reinterpret_cast<const float4*>(&al_s4[s * 4]);
  const float4 ad = *reinterpret_cast<const float4*>(&al_d4[d * 4]);
  float4 ev;
  ev.x = as.x + ad.x; ev.x = (ev.x > 0.f) ? ev.x : NEG_SLOPE * ev.x;
  ev.y = as.y + ad.y; ev.y = (ev.y > 0.f) ? ev.y : NEG_SLOPE * ev.y;
  ev.z = as.z + ad.z; ev.z = (ev.z > 0.f) ? ev.z : NEG_SLOPE * ev.z;
  ev.w = as.w + ad.w; ev.w = (ev.w > 0.f) ? ev.w : NEG_SLOPE * ev.w;
  e4[i] = ev;
}

// ---------------------------------------------------------------------------
// Aggregate with fused softmax stats. Wave per dst (4 dst/block).
// ---------------------------------------------------------------------------
template <typename OT>
__global__ __launch_bounds__(256) void agg_kernel(
    const _Float16* __restrict__ h16, const float* __restrict__ e4f,
    const int* __restrict__ row_ptr, const int* __restrict__ ssrc,
    const float* __restrict__ bias, OT* __restrict__ out, int n) {
  const int d = blockIdx.x * 4 + (threadIdx.x >> 6);
  if (d >= n) return;
  const int lane = threadIdx.x & 63;
  const int start = row_ptr[d];
  const int end = row_ptr[d + 1];

  // phase 1: per-head max & sum (wave-parallel over segment)
  float4 mv = make_float4(-INFINITY, -INFINITY, -INFINITY, -INFINITY);
  for (int i = start + lane; i < end; i += 64) {
    const float4 v = *reinterpret_cast<const float4*>(&e4f[i * 4]);
    mv.x = fmaxf(mv.x, v.x); mv.y = fmaxf(mv.y, v.y);
    mv.z = fmaxf(mv.z, v.z); mv.w = fmaxf(mv.w, v.w);
  }
#pragma unroll
  for (int msk = 32; msk >= 1; msk >>= 1) {
    mv.x = fmaxf(mv.x, __shfl_xor(mv.x, msk));
    mv.y = fmaxf(mv.y, __shfl_xor(mv.y, msk));
    mv.z = fmaxf(mv.z, __shfl_xor(mv.z, msk));
    mv.w = fmaxf(mv.w, __shfl_xor(mv.w, msk));
  }
  float4 Sv = make_float4(0.f, 0.f, 0.f, 0.f);
  for (int i = start + lane; i < end; i += 64) {
    const float4 v = *reinterpret_cast<const float4*>(&e4f[i * 4]);
    Sv.x += __expf(v.x - mv.x); Sv.y += __expf(v.y - mv.y);
    Sv.z += __expf(v.z - mv.z); Sv.w += __expf(v.w - mv.w);
  }
#pragma unroll
  for (int msk = 32; msk >= 1; msk >>= 1) {
    Sv.x += __shfl_xor(Sv.x, msk);
    Sv.y += __shfl_xor(Sv.y, msk);
    Sv.z += __shfl_xor(Sv.z, msk);
    Sv.w += __shfl_xor(Sv.w, msk);
  }
  const int head = lane >> 4;
  const float m_h = (head == 0) ? mv.x : (head == 1) ? mv.y : (head == 2) ? mv.z : mv.w;
  const float S_h = (head == 0) ? Sv.x : (head == 1) ? Sv.y : (head == 2) ? Sv.z : Sv.w;
  const float r_h = 1.f / (S_h + 1e-16f);

  // phase 2: weighted gather
  const int c0 = lane * 4;
  float a0 = 0.f, a1 = 0.f, a2 = 0.f, a3 = 0.f;
  int i = start;
  for (; i + 1 < end; i += 2) {
    const int s0 = ssrc[i];
    const int s1 = ssrc[i + 1];
    const float pa = __expf(e4f[i * 4 + head] - m_h);
    const float pb = __expf(e4f[(i + 1) * 4 + head] - m_h);
    const f16x4 h0 = *reinterpret_cast<const f16x4*>(&h16[(size_t)s0 * HID + c0]);
    const f16x4 h1 = *reinterpret_cast<const f16x4*>(&h16[(size_t)s1 * HID + c0]);
    a0 += pa * (float)h0.x + pb * (float)h1.x;
    a1 += pa * (float)h0.y + pb * (float)h1.y;
    a2 += pa * (float)h0.z + pb * (float)h1.z;
    a3 += pa * (float)h0.w + pb * (float)h1.w;
  }
  if (i < end) {
    const int s0 = ssrc[i];
    const float pa = __expf(e4f[i * 4 + head] - m_h);
    const f16x4 h0 = *reinterpret_cast<const f16x4*>(&h16[(size_t)s0 * HID + c0]);
    a0 += pa * (float)h0.x;
    a1 += pa * (float)h0.y;
    a2 += pa * (float)h0.z;
    a3 += pa * (float)h0.w;
  }
  const float4 bv = *reinterpret_cast<const float4*>(&bias[c0]);
  if (sizeof(OT) == 2) {
    f16x4 o = {(_Float16)(a0 * r_h + bv.x), (_Float16)(a1 * r_h + bv.y),
               (_Float16)(a2 * r_h + bv.z), (_Float16)(a3 * r_h + bv.w)};
    *reinterpret_cast<f16x4*>(&((_Float16*)out)[(size_t)d * HID + c0]) = o;
  } else {
    float4 o = make_float4(a0 * r_h + bv.x, a1 * r_h + bv.y, a2 * r_h + bv.z,
                           a3 * r_h + bv.w);
    *reinterpret_cast<float4*>(&((float*)out)[(size_t)d * HID + c0]) = o;
  }
}

// ---------------------------------------------------------------------------
static inline char* align16(char* p) {
  return (char*)(((size_t)p + 15) & ~(size_t)15);
}

extern "C" void kernel_launch(void* const* d_in, const int* in_sizes, int n_in,
                              void* d_out, int out_size, void* d_ws, size_t ws_size,
                              hipStream_t stream) {
  const float* x   = (const float*)d_in[0];
  const int* esrc  = (const int*)d_in[1];
  const int* edst  = (const int*)d_in[2];
  const float* W1  = (const float*)d_in[3];
  const float* a1s = (const float*)d_in[4];
  const float* a1d = (const float*)d_in[5];
  const float* b1  = (const float*)d_in[6];
  const float* W2  = (const float*)d_in[7];
  const float* a2s = (const float*)d_in[8];
  const float* a2d = (const float*)d_in[9];
  const float* b2  = (const float*)d_in[10];
  float* out = (float*)d_out;

  const int N = in_sizes[0] / IN_DIM;  // 20000
  const int E = in_sizes[1];           // 320000
  const int ET = E + N;

  char* ws = (char*)d_ws;
  _Float16* h16 = (_Float16*)ws;  ws = align16(ws + (size_t)N * HID * 2);
  _Float16* x116 = (_Float16*)ws; ws = align16(ws + (size_t)N * HID * 2);
  float* al_s4 = (float*)ws;      ws = align16(ws + (size_t)N * HEADS * 4);
  float* al_d4 = (float*)ws;      ws = align16(ws + (size_t)N * HEADS * 4);
  int* row_ptr = (int*)ws;        ws = align16(ws + (size_t)(N + 8) * 4);
  int* deg = (int*)ws;            ws = align16(ws + (size_t)(N + 8) * 4);
  int* cursor = (int*)ws;         ws = align16(ws + (size_t)N * 4);
  int* ssrc = (int*)ws;           ws = align16(ws + (size_t)ET * 4);
  int* sdst = (int*)ws;           ws = align16(ws + (size_t)ET * 4);
  float4* e4 = (float4*)ws;       ws = align16(ws + (size_t)ET * 16);
  _Float16* W1t = (_Float16*)ws;  ws = align16(ws + (size_t)HID * IN_DIM * 2);
  _Float16* W2t = (_Float16*)ws;  ws = align16(ws + (size_t)HID * HID * 2);

  hipMemsetAsync(deg, 0, (size_t)(N + 8) * 4, stream);
  hipMemsetAsync(cursor, 0, (size_t)N * 4, stream);

  const int thr = 256;
  const int hgrid = (ET + thr - 1) / thr;
  prep_kernel<<<G1 + G2 + hgrid, thr, 0, stream>>>(W1, W1t, W2, W2t, edst, deg,
                                                   E, ET);
  scan_kernel<<<1, 1024, 0, stream>>>(deg, row_ptr, N);

  const int ggrid = (N + 15) / 16;     // 1250 blocks
  const int egrid = (ET + thr - 1) / thr;
  const int agrid = (N + 3) / 4;

  // ---- layer 1
  gemm_stream<false, IN_DIM><<<ggrid, 256, 0, stream>>>(x, W1t, h16, a1s, a1d,
                                                        al_s4, al_d4, N);
  scatter_kernel<<<egrid, thr, 0, stream>>>(esrc, edst, row_ptr, cursor, ssrc,
                                            sdst, al_s4, al_d4, e4, E, ET);
  agg_kernel<_Float16><<<agrid, 256, 0, stream>>>(h16, (const float*)e4, row_ptr,
                                                  ssrc, b1, x116, N);
  // ---- layer 2
  gemm_stream<true, HID><<<ggrid, 256, 0, stream>>>(x116, W2t, h16, a2s, a2d,
                                                    al_s4, al_d4, N);
  logits_kernel<<<egrid, thr, 0, stream>>>(al_s4, al_d4, ssrc, sdst, e4, ET);
  agg_kernel<float><<<agrid, 256, 0, stream>>>(h16, (const float*)e4, row_ptr,
                                               ssrc, b2, out, N);
}

// Round 11
// 178.451 us; speedup vs baseline: 1.3141x; 1.3141x over previous
//
#include <hip/hip_runtime.h>
#include <math.h>

#define HEADS 4
#define CH 64
#define HID 256
#define IN_DIM 768
#define NEG_SLOPE 0.2f

typedef _Float16 f16x8 __attribute__((ext_vector_type(8)));
typedef _Float16 f16x4 __attribute__((ext_vector_type(4)));
typedef float f32x4 __attribute__((ext_vector_type(4)));

__device__ __forceinline__ void async16(void* lds, const void* g) {
  __builtin_amdgcn_global_load_lds(
      (const __attribute__((address_space(1))) unsigned int*)g,
      (__attribute__((address_space(3))) unsigned int*)lds, 16, 0, 0);
}

// ---------------------------------------------------------------------------
// prep: wconv W1 + wconv W2 + degree histogram, fused (block-range split)
// ---------------------------------------------------------------------------
#define G1 768   /* IN_DIM*HID/256 */
#define G2 256   /* HID*HID/256 */
__global__ void prep_kernel(const float* __restrict__ W1, _Float16* __restrict__ W1t,
                            const float* __restrict__ W2, _Float16* __restrict__ W2t,
                            const int* __restrict__ edge_dst, int* __restrict__ deg,
                            int E, int ET) {
  const int b = blockIdx.x;
  if (b < G1) {
    const int idx = b * 256 + threadIdx.x;
    const int k = idx >> 8, n = idx & 255;
    W1t[(size_t)n * IN_DIM + k] = (_Float16)W1[idx];
  } else if (b < G1 + G2) {
    const int idx = (b - G1) * 256 + threadIdx.x;
    const int k = idx >> 8, n = idx & 255;
    W2t[(size_t)n * HID + k] = (_Float16)W2[idx];
  } else {
    const int e = (b - G1 - G2) * 256 + threadIdx.x;
    if (e < ET) {
      const int d = (e < E) ? edge_dst[e] : (e - E);
      atomicAdd(&deg[d], 1);
    }
  }
}

// ---------------------------------------------------------------------------
// DMA-staged double-buffered GEMM, tile 32x128, BK=32, 128 thr = 2 waves
// (each wave: 32 rows x 64 cols = one head). Small tile -> 1250 blocks,
// ~4.9/CU resident (24KB dbuf LDS) -> many concurrent DMA streams (the
// measured duty-cycle lever: R8 4.9/CU=2.9TB/s vs R9 2/CU=1.8TB/s) at 1x
// A fetch volume (grid-y=2, twin absorbed by L3). One barrier per K-tile:
//   stage(buf^1, kt+1) -> compute(buf) -> barrier -> swap.
// XOR-swizzle via pre-swizzled GLOBAL source + swizzled read (rule 21).
// Fused per-wave alpha epilogue.
// ---------------------------------------------------------------------------
template <bool AF16, int K>
__global__ __launch_bounds__(128, 3) void gemm_dma(
    const void* __restrict__ Av, const _Float16* __restrict__ Bt,
    _Float16* __restrict__ C, const float* __restrict__ a_src,
    const float* __restrict__ a_dst, float* __restrict__ al_s4,
    float* __restrict__ al_d4, int M) {
  constexpr int NT = K / 32;
  constexpr int ASZ = AF16 ? 2048 : 4096;   // 32 rows x 32 k
  constexpr int BSZ = 8192;                 // 128 cols x 32 k fp16
  __shared__ char smem[2 * (ASZ + BSZ)];

  const int t = threadIdx.x;
  const int lane = t & 63;
  const int wv = t >> 6;            // wave -> 64-col strip == head within block
  const int row0 = blockIdx.x * 32;
  const int col0 = blockIdx.y * 128;
  const int hd = blockIdx.y * 2 + wv;
  const int rl = lane & 15;
  const int qk = lane >> 4;

  const float* A32 = (const float*)Av;
  const _Float16* A16 = (const _Float16*)Av;

  f32x4 acc[2][4] = {};

  auto stage = [&](int b, int kt) {
    char* Ab = smem + b * (ASZ + BSZ);
    char* Bb = Ab + ASZ;
    if (!AF16) {
      // A fp32 [32 rows][32 k]=4KB; row=128B=8 chunks; swizzle c^(row&7)
#pragma unroll
      for (int j = 0; j < 2; ++j) {
        const int s = j * 128 + t;
        const int row = s >> 3, c = s & 7;
        const int rg = min(row0 + row, M - 1);
        async16(Ab + s * 16, A32 + (size_t)rg * K + kt * 32 + ((c ^ (row & 7)) << 2));
      }
    } else {
      // A fp16 [32][32]=2KB; row=64B=4 chunks; swizzle c^(r&3)^((r>>2)&3)
      {
        const int s = t;                     // 128 chunks total
        const int row = s >> 2, c = s & 3;
        const int rg = min(row0 + row, M - 1);
        const int cp = c ^ (row & 3) ^ ((row >> 2) & 3);
        async16(Ab + s * 16, A16 + (size_t)rg * K + kt * 32 + (cp << 3));
      }
    }
    // B fp16 [128 cols][32 k]=8KB; col=64B=4 chunks; swizzle c^(c&3 bits of col)
#pragma unroll
    for (int j = 0; j < 4; ++j) {
      const int s = j * 128 + t;
      const int col = s >> 2, c = s & 3;
      const int cp = c ^ (col & 3) ^ ((col >> 2) & 3);
      async16(Bb + s * 16, Bt + (size_t)(col0 + col) * K + kt * 32 + (cp << 3));
    }
  };

  auto compute = [&](int b) {
    const char* Ab = smem + b * (ASZ + BSZ);
    const char* Bb = Ab + ASZ;
    f16x8 af[2], bf[4];
#pragma unroll
    for (int m = 0; m < 2; ++m) {
      const int R = m * 16 + rl;            // R&7 == rl&7, R&3 == rl&3
      if (AF16) {
        const int c = qk ^ (rl & 3) ^ ((rl >> 2) & 3);
        af[m] = *reinterpret_cast<const f16x8*>(Ab + R * 64 + c * 16);
      } else {
        const int c0 = (2 * qk) ^ (rl & 7);
        const int c1 = (2 * qk + 1) ^ (rl & 7);
        const f32x4 lo = *reinterpret_cast<const f32x4*>(Ab + R * 128 + c0 * 16);
        const f32x4 hi = *reinterpret_cast<const f32x4*>(Ab + R * 128 + c1 * 16);
        af[m] = (f16x8){(_Float16)lo[0], (_Float16)lo[1], (_Float16)lo[2],
                        (_Float16)lo[3], (_Float16)hi[0], (_Float16)hi[1],
                        (_Float16)hi[2], (_Float16)hi[3]};
      }
    }
#pragma unroll
    for (int n = 0; n < 4; ++n) {
      const int Cc = wv * 64 + n * 16 + rl;  // Cc&3==rl&3, (Cc>>2)&3==(rl>>2)&3
      const int c = qk ^ (rl & 3) ^ ((rl >> 2) & 3);
      bf[n] = *reinterpret_cast<const f16x8*>(Bb + Cc * 64 + c * 16);
    }
#pragma unroll
    for (int m = 0; m < 2; ++m)
#pragma unroll
      for (int n = 0; n < 4; ++n)
        acc[m][n] = __builtin_amdgcn_mfma_f32_16x16x32_f16(af[m], bf[n],
                                                           acc[m][n], 0, 0, 0);
  };

  stage(0, 0);
  __syncthreads();                  // buf0 DMA complete
  int cur = 0;
  for (int kt = 0; kt < NT; ++kt) {
    if (kt + 1 < NT) stage(cur ^ 1, kt + 1);  // issue next DMA first
    compute(cur);                             // hide DMA under compute
    __syncthreads();                // reads of cur done + next DMA complete
    cur ^= 1;
  }

  // ---- C store (frag: row=(lane>>4)*4+r, col=lane&15)
#pragma unroll
  for (int m = 0; m < 2; ++m)
#pragma unroll
    for (int n = 0; n < 4; ++n)
#pragma unroll
      for (int r = 0; r < 4; ++r) {
        const int gr = row0 + m * 16 + qk * 4 + r;
        if (gr < M)
          C[(size_t)gr * HID + col0 + wv * 64 + n * 16 + rl] =
              (_Float16)acc[m][n][r];
      }

  // ---- fused alpha (wave owns head hd for the block's 32 rows)
  const float as0 = a_src[hd * CH + rl];
  const float as1 = a_src[hd * CH + 16 + rl];
  const float as2 = a_src[hd * CH + 32 + rl];
  const float as3 = a_src[hd * CH + 48 + rl];
  const float ad0 = a_dst[hd * CH + rl];
  const float ad1 = a_dst[hd * CH + 16 + rl];
  const float ad2 = a_dst[hd * CH + 32 + rl];
  const float ad3 = a_dst[hd * CH + 48 + rl];
#pragma unroll
  for (int m = 0; m < 2; ++m) {
#pragma unroll
    for (int r = 0; r < 4; ++r) {
      float vs = acc[m][0][r] * as0 + acc[m][1][r] * as1 +
                 acc[m][2][r] * as2 + acc[m][3][r] * as3;
      float vd = acc[m][0][r] * ad0 + acc[m][1][r] * ad1 +
                 acc[m][2][r] * ad2 + acc[m][3][r] * ad3;
      vs += __shfl_xor(vs, 1); vs += __shfl_xor(vs, 2);
      vs += __shfl_xor(vs, 4); vs += __shfl_xor(vs, 8);
      vd += __shfl_xor(vd, 1); vd += __shfl_xor(vd, 2);
      vd += __shfl_xor(vd, 4); vd += __shfl_xor(vd, 8);
      const int gr = row0 + m * 16 + qk * 4 + r;
      if (rl == 0 && gr < M) {
        al_s4[gr * HEADS + hd] = vs;
        al_d4[gr * HEADS + hd] = vd;
      }
    }
  }
}

// ---------------------------------------------------------------------------
// x4-vectorized single-block scan
// ---------------------------------------------------------------------------
__global__ __launch_bounds__(1024) void scan_kernel(const int* __restrict__ deg,
                                                    int* __restrict__ row_ptr, int n) {
  __shared__ int wsum[16];
  __shared__ int carry_s;
  const int t = threadIdx.x, lane = t & 63, w = t >> 6;
  if (t == 0) {
    carry_s = 0;
    row_ptr[0] = 0;
  }
  __syncthreads();
  for (int base = 0; base < n; base += 4096) {
    const int i0 = base + t * 4;
    int4 v = make_int4(0, 0, 0, 0);
    if (i0 < n) v = *reinterpret_cast<const int4*>(&deg[i0]);
    const int s0 = v.x, s1 = s0 + v.y, s2 = s1 + v.z, s3 = s2 + v.w;
    int x = s3;
#pragma unroll
    for (int off = 1; off < 64; off <<= 1) {
      int y = __shfl_up(x, off);
      if (lane >= off) x += y;
    }
    if (lane == 63) wsum[w] = x;
    __syncthreads();
    if (w == 0) {
      int s = (lane < 16) ? wsum[lane] : 0;
#pragma unroll
      for (int off = 1; off < 16; off <<= 1) {
        int y = __shfl_up(s, off);
        if (lane >= off) s += y;
      }
      if (lane < 16) wsum[lane] = s;
    }
    __syncthreads();
    const int woff = (w > 0) ? wsum[w - 1] : 0;
    const int pre = carry_s + woff + x - s3;
    if (i0 < n) {
      row_ptr[i0 + 1] = pre + s0;
      row_ptr[i0 + 2] = pre + s1;
      row_ptr[i0 + 3] = pre + s2;
      row_ptr[i0 + 4] = pre + s3;
    }
    __syncthreads();
    if (t == 1023) carry_s = pre + s3;
    __syncthreads();
  }
}

// ---------------------------------------------------------------------------
// scatter + layer-1 logits fused (after GEMM1)
// ---------------------------------------------------------------------------
__global__ void scatter_kernel(const int* __restrict__ edge_src,
                               const int* __restrict__ edge_dst,
                               const int* __restrict__ row_ptr,
                               int* __restrict__ cursor,
                               int* __restrict__ ssrc, int* __restrict__ sdst,
                               const float* __restrict__ al_s4,
                               const float* __restrict__ al_d4,
                               float4* __restrict__ e4, int E, int ET) {
  const int e = blockIdx.x * blockDim.x + threadIdx.x;
  if (e < ET) {
    int d, s;
    if (e < E) {
      d = edge_dst[e];
      s = edge_src[e];
    } else {
      d = s = e - E;
    }
    const int pos = row_ptr[d] + atomicAdd(&cursor[d], 1);
    ssrc[pos] = s;
    sdst[pos] = d;
    const float4 as = *reinterpret_cast<const float4*>(&al_s4[s * 4]);
    const float4 ad = *reinterpret_cast<const float4*>(&al_d4[d * 4]);
    float4 ev;
    ev.x = as.x + ad.x; ev.x = (ev.x > 0.f) ? ev.x : NEG_SLOPE * ev.x;
    ev.y = as.y + ad.y; ev.y = (ev.y > 0.f) ? ev.y : NEG_SLOPE * ev.y;
    ev.z = as.z + ad.z; ev.z = (ev.z > 0.f) ? ev.z : NEG_SLOPE * ev.z;
    ev.w = as.w + ad.w; ev.w = (ev.w > 0.f) ? ev.w : NEG_SLOPE * ev.w;
    e4[pos] = ev;
  }
}

// layer-2 logits (CSR order already built)
__global__ __launch_bounds__(256) void logits_kernel(
    const float* __restrict__ al_s4, const float* __restrict__ al_d4,
    const int* __restrict__ ssrc, const int* __restrict__ sdst,
    float4* __restrict__ e4, int ET) {
  const int i = blockIdx.x * blockDim.x + threadIdx.x;
  if (i >= ET) return;
  const int s = ssrc[i];
  const int d = sdst[i];
  const float4 as = *reinterpret_cast<const float4*>(&al_s4[s * 4]);
  const float4 ad = *reinterpret_cast<const float4*>(&al_d4[d * 4]);
  float4 ev;
  ev.x = as.x + ad.x; ev.x = (ev.x > 0.f) ? ev.x : NEG_SLOPE * ev.x;
  ev.y = as.y + ad.y; ev.y = (ev.y > 0.f) ? ev.y : NEG_SLOPE * ev.y;
  ev.z = as.z + ad.z; ev.z = (ev.z > 0.f) ? ev.z : NEG_SLOPE * ev.z;
  ev.w = as.w + ad.w; ev.w = (ev.w > 0.f) ? ev.w : NEG_SLOPE * ev.w;
  e4[i] = ev;
}

// ---------------------------------------------------------------------------
// Aggregate with fused softmax stats. Wave per dst (4 dst/block).
// ---------------------------------------------------------------------------
template <typename OT>
__global__ __launch_bounds__(256) void agg_kernel(
    const _Float16* __restrict__ h16, const float* __restrict__ e4f,
    const int* __restrict__ row_ptr, const int* __restrict__ ssrc,
    const float* __restrict__ bias, OT* __restrict__ out, int n) {
  const int d = blockIdx.x * 4 + (threadIdx.x >> 6);
  if (d >= n) return;
  const int lane = threadIdx.x & 63;
  const int start = row_ptr[d];
  const int end = row_ptr[d + 1];

  // phase 1: per-head max & sum (wave-parallel over segment)
  float4 mv = make_float4(-INFINITY, -INFINITY, -INFINITY, -INFINITY);
  for (int i = start + lane; i < end; i += 64) {
    const float4 v = *reinterpret_cast<const float4*>(&e4f[i * 4]);
    mv.x = fmaxf(mv.x, v.x); mv.y = fmaxf(mv.y, v.y);
    mv.z = fmaxf(mv.z, v.z); mv.w = fmaxf(mv.w, v.w);
  }
#pragma unroll
  for (int msk = 32; msk >= 1; msk >>= 1) {
    mv.x = fmaxf(mv.x, __shfl_xor(mv.x, msk));
    mv.y = fmaxf(mv.y, __shfl_xor(mv.y, msk));
    mv.z = fmaxf(mv.z, __shfl_xor(mv.z, msk));
    mv.w = fmaxf(mv.w, __shfl_xor(mv.w, msk));
  }
  float4 Sv = make_float4(0.f, 0.f, 0.f, 0.f);
  for (int i = start + lane; i < end; i += 64) {
    const float4 v = *reinterpret_cast<const float4*>(&e4f[i * 4]);
    Sv.x += __expf(v.x - mv.x); Sv.y += __expf(v.y - mv.y);
    Sv.z += __expf(v.z - mv.z); Sv.w += __expf(v.w - mv.w);
  }
#pragma unroll
  for (int msk = 32; msk >= 1; msk >>= 1) {
    Sv.x += __shfl_xor(Sv.x, msk);
    Sv.y += __shfl_xor(Sv.y, msk);
    Sv.z += __shfl_xor(Sv.z, msk);
    Sv.w += __shfl_xor(Sv.w, msk);
  }
  const int head = lane >> 4;
  const float m_h = (head == 0) ? mv.x : (head == 1) ? mv.y : (head == 2) ? mv.z : mv.w;
  const float S_h = (head == 0) ? Sv.x : (head == 1) ? Sv.y : (head == 2) ? Sv.z : Sv.w;
  const float r_h = 1.f / (S_h + 1e-16f);

  // phase 2: weighted gather
  const int c0 = lane * 4;
  float a0 = 0.f, a1 = 0.f, a2 = 0.f, a3 = 0.f;
  int i = start;
  for (; i + 1 < end; i += 2) {
    const int s0 = ssrc[i];
    const int s1 = ssrc[i + 1];
    const float pa = __expf(e4f[i * 4 + head] - m_h);
    const float pb = __expf(e4f[(i + 1) * 4 + head] - m_h);
    const f16x4 h0 = *reinterpret_cast<const f16x4*>(&h16[(size_t)s0 * HID + c0]);
    const f16x4 h1 = *reinterpret_cast<const f16x4*>(&h16[(size_t)s1 * HID + c0]);
    a0 += pa * (float)h0.x + pb * (float)h1.x;
    a1 += pa * (float)h0.y + pb * (float)h1.y;
    a2 += pa * (float)h0.z + pb * (float)h1.z;
    a3 += pa * (float)h0.w + pb * (float)h1.w;
  }
  if (i < end) {
    const int s0 = ssrc[i];
    const float pa = __expf(e4f[i * 4 + head] - m_h);
    const f16x4 h0 = *reinterpret_cast<const f16x4*>(&h16[(size_t)s0 * HID + c0]);
    a0 += pa * (float)h0.x;
    a1 += pa * (float)h0.y;
    a2 += pa * (float)h0.z;
    a3 += pa * (float)h0.w;
  }
  const float4 bv = *reinterpret_cast<const float4*>(&bias[c0]);
  if (sizeof(OT) == 2) {
    f16x4 o = {(_Float16)(a0 * r_h + bv.x), (_Float16)(a1 * r_h + bv.y),
               (_Float16)(a2 * r_h + bv.z), (_Float16)(a3 * r_h + bv.w)};
    *reinterpret_cast<f16x4*>(&((_Float16*)out)[(size_t)d * HID + c0]) = o;
  } else {
    float4 o = make_float4(a0 * r_h + bv.x, a1 * r_h + bv.y, a2 * r_h + bv.z,
                           a3 * r_h + bv.w);
    *reinterpret_cast<float4*>(&((float*)out)[(size_t)d * HID + c0]) = o;
  }
}

// ---------------------------------------------------------------------------
static inline char* align16(char* p) {
  return (char*)(((size_t)p + 15) & ~(size_t)15);
}

extern "C" void kernel_launch(void* const* d_in, const int* in_sizes, int n_in,
                              void* d_out, int out_size, void* d_ws, size_t ws_size,
                              hipStream_t stream) {
  const float* x   = (const float*)d_in[0];
  const int* esrc  = (const int*)d_in[1];
  const int* edst  = (const int*)d_in[2];
  const float* W1  = (const float*)d_in[3];
  const float* a1s = (const float*)d_in[4];
  const float* a1d = (const float*)d_in[5];
  const float* b1  = (const float*)d_in[6];
  const float* W2  = (const float*)d_in[7];
  const float* a2s = (const float*)d_in[8];
  const float* a2d = (const float*)d_in[9];
  const float* b2  = (const float*)d_in[10];
  float* out = (float*)d_out;

  const int N = in_sizes[0] / IN_DIM;  // 20000
  const int E = in_sizes[1];           // 320000
  const int ET = E + N;

  char* ws = (char*)d_ws;
  _Float16* h16 = (_Float16*)ws;  ws = align16(ws + (size_t)N * HID * 2);
  _Float16* x116 = (_Float16*)ws; ws = align16(ws + (size_t)N * HID * 2);
  float* al_s4 = (float*)ws;      ws = align16(ws + (size_t)N * HEADS * 4);
  float* al_d4 = (float*)ws;      ws = align16(ws + (size_t)N * HEADS * 4);
  int* row_ptr = (int*)ws;        ws = align16(ws + (size_t)(N + 8) * 4);
  int* deg = (int*)ws;            ws = align16(ws + (size_t)(N + 8) * 4);
  int* cursor = (int*)ws;         ws = align16(ws + (size_t)N * 4);
  int* ssrc = (int*)ws;           ws = align16(ws + (size_t)ET * 4);
  int* sdst = (int*)ws;           ws = align16(ws + (size_t)ET * 4);
  float4* e4 = (float4*)ws;       ws = align16(ws + (size_t)ET * 16);
  _Float16* W1t = (_Float16*)ws;  ws = align16(ws + (size_t)HID * IN_DIM * 2);
  _Float16* W2t = (_Float16*)ws;  ws = align16(ws + (size_t)HID * HID * 2);

  hipMemsetAsync(deg, 0, (size_t)(N + 8) * 4, stream);
  hipMemsetAsync(cursor, 0, (size_t)N * 4, stream);

  const int thr = 256;
  const int hgrid = (ET + thr - 1) / thr;
  prep_kernel<<<G1 + G2 + hgrid, thr, 0, stream>>>(W1, W1t, W2, W2t, edst, deg,
                                                   E, ET);
  scan_kernel<<<1, 1024, 0, stream>>>(deg, row_ptr, N);

  dim3 ggrid((N + 31) / 32, HID / 128);   // (625, 2) = 1250 blocks
  const int egrid = (ET + thr - 1) / thr;
  const int agrid = (N + 3) / 4;

  // ---- layer 1
  gemm_dma<false, IN_DIM><<<ggrid, 128, 0, stream>>>(x, W1t, h16, a1s, a1d,
                                                     al_s4, al_d4, N);
  scatter_kernel<<<egrid, thr, 0, stream>>>(esrc, edst, row_ptr, cursor, ssrc,
                                            sdst, al_s4, al_d4, e4, E, ET);
  agg_kernel<_Float16><<<agrid, 256, 0, stream>>>(h16, (const float*)e4, row_ptr,
                                                  ssrc, b1, x116, N);
  // ---- layer 2
  gemm_dma<true, HID><<<ggrid, 128, 0, stream>>>(x116, W2t, h16, a2s, a2d,
                                                 al_s4, al_d4, N);
  logits_kernel<<<egrid, thr, 0, stream>>>(al_s4, al_d4, ssrc, sdst, e4, ET);
  agg_kernel<float><<<agrid, 256, 0, stream>>>(h16, (const float*)e4, row_ptr,
                                               ssrc, b2, out, N);
}